// Round 5
// baseline (139.187 us; speedup 1.0000x reference)
//
#include <hip/hip_runtime.h>

// CRF loss on MI355X — staggered 2-phase pipeline, 2 batches per wave,
// inline-asm DS exchange with counted lgkmcnt (round 5 = round 4 + T4).
// B=512, L=512, T=32, S=34. Output f32[512].
//
// Same dataflow/numerics as round 4 (verified absmax 0.0). Change: the
// per-slot exchange (ds_write_b32 publish + 8x ds_read_b128 broadcast) is
// inline asm invisible to the compiler's waitcnt pass; each slot waits
// s_waitcnt lgkmcnt(1) -- forcing only the PREVIOUS slot's reads complete
// while this slot's publish stays in flight -- then sched_barrier(0)
// (guide rule 18) pins the FMA below the wait. This guarantees graduated
// waits (the compiler may otherwise emit lgkmcnt(0) per slot, draining the
// just-issued partner reads and exposing full LDS latency every slot).
// Outstanding DS ops <= 10 < 15 (counter width). The rescale's ds_swizzle
// (1/16 steps) and the epilogue drain everything, so compiler-inserted
// waits never under-count.

typedef float f32x4 __attribute__((ext_vector_type(4)));

#define F2   1.4426950408889634f   // log2(e)
#define LN2  0.6931471805599453f
#define BIAS 0.0078125f            // 2^-7, exact
#define BIASCNT 3577               // 7 * 511 applications of biased tc

// 8x ds_read_b128 from one base address (offsets 0..112): the 32-float
// broadcast read of one chain region. Early-clobber so outputs never alias
// the address register.
#define DS_RD8(r, a)                                                         \
  asm volatile("ds_read_b128 %0, %8 offset:0\n\t"                            \
               "ds_read_b128 %1, %8 offset:16\n\t"                           \
               "ds_read_b128 %2, %8 offset:32\n\t"                           \
               "ds_read_b128 %3, %8 offset:48\n\t"                           \
               "ds_read_b128 %4, %8 offset:64\n\t"                           \
               "ds_read_b128 %5, %8 offset:80\n\t"                           \
               "ds_read_b128 %6, %8 offset:96\n\t"                           \
               "ds_read_b128 %7, %8 offset:112"                              \
               : "=&v"((r)[0]), "=&v"((r)[1]), "=&v"((r)[2]), "=&v"((r)[3]), \
                 "=&v"((r)[4]), "=&v"((r)[5]), "=&v"((r)[6]), "=&v"((r)[7])  \
               : "v"(a))

#define DS_WR(a, x) asm volatile("ds_write_b32 %0, %1" :: "v"(a), "v"(x))

// counted wait: previous slot's 8 reads + write complete; newest 1 op
// (this slot's publish) may remain in flight. sched_barrier pins code below.
#define LGKM1() do { asm volatile("s_waitcnt lgkmcnt(1)");                   \
                     __builtin_amdgcn_sched_barrier(0); } while (0)

__device__ __forceinline__ float grpmax32(float x) {
    // max over each 32-lane half: 4 DPP row_ror fmax + ds_swizzle xor-16.
    int t;
    t = __builtin_amdgcn_update_dpp(__float_as_int(x), __float_as_int(x), 0x121, 0xf, 0xf, true);
    x = fmaxf(x, __int_as_float(t));   // row_ror:1
    t = __builtin_amdgcn_update_dpp(__float_as_int(x), __float_as_int(x), 0x122, 0xf, 0xf, true);
    x = fmaxf(x, __int_as_float(t));   // row_ror:2
    t = __builtin_amdgcn_update_dpp(__float_as_int(x), __float_as_int(x), 0x124, 0xf, 0xf, true);
    x = fmaxf(x, __int_as_float(t));   // row_ror:4
    t = __builtin_amdgcn_update_dpp(__float_as_int(x), __float_as_int(x), 0x128, 0xf, 0xf, true);
    x = fmaxf(x, __int_as_float(t));   // row_ror:8
    t = __builtin_amdgcn_ds_swizzle(__float_as_int(x), 0x401F);  // xor 16
    x = fmaxf(x, __int_as_float(t));
    return x;
}

__global__ __launch_bounds__(64) void crf_kernel(
    const float* __restrict__ wtv,    // [512,512,32]
    const float* __restrict__ trans,  // [34,34]
    const int*   __restrict__ rtag,   // [512,512]
    float* __restrict__ out)          // [512]
{
    __shared__ __align__(16) float tlds[1156];  // raw translation (ln domain)
    __shared__ __align__(16) int   ltag[1024];  // gold tags, 2 batches
    __shared__ __align__(16) float alds[160];   // F: q*36+[0..31]; B: 80+q*36+[0..31]

    const int l = threadIdx.x;
    const int q = l >> 5;        // batch within pair
    const int c = l & 31;        // state-1
    const int bbase = blockIdx.x * 2;

    for (int k = l; k < 1156; k += 64) tlds[k] = trans[k];
    {
        const int* rtb = rtag + (size_t)bbase * 512;
        for (int k = l; k < 1024; k += 64) ltag[k] = rtb[k];
    }
    __syncthreads();  // once, before the main loop (graph-safe)

    // exp2-domain transitions, exact 2^-7 bias folded in
    float tcF[32], tcB[32];
    #pragma unroll
    for (int k = 0; k < 32; ++k) {
        tcF[k] = __builtin_exp2f(F2 * tlds[(k + 1) * 34 + (c + 1)]) * BIAS; // col c+1
        tcB[k] = __builtin_exp2f(F2 * tlds[(c + 1) * 34 + (k + 1)]) * BIAS; // row c+1
    }
    float aiF = __builtin_exp2f(F2 * tlds[c + 1]) * BIAS;  // START term, step 1 only

    const float* wbq = wtv + (size_t)(bbase + q) * (512 * 32);

    float stF = __builtin_exp2f(F2 * wbq[c]);   // alpha_0 (row-0 emission)
    float stB = 1.0f;                           // b_511
    int scF = 0, scB = 0;

    // emission pipeline: refilled 8 steps ahead inside the slot shadows
    float vnF[16], vnB[16];
    #pragma unroll
    for (int j = 0; j < 8; ++j) {
        vnF[j] = wbq[(1 + j) * 32 + c];        // rows 1..8
        vnB[j] = wbq[(511 - j) * 32 + c];      // rows 511..504
    }
    float eoF_c = __builtin_exp2f(F2 * vnF[0]);        // emission factor, step 1
    float gB    = stB * __builtin_exp2f(F2 * vnB[0]);  // bwd publish value, step 1

    // raw LDS byte addresses (low 32 bits of the flat shared address = LDS
    // offset on gfx9+: shared aperture is 4GB-aligned)
    const unsigned abase  = (unsigned)(size_t)(void*)alds;
    const unsigned addrF  = abase + (unsigned)(q * 144);        // fwd region
    const unsigned addrB  = abase + 320u + (unsigned)(q * 144); // bwd region
    const unsigned addrFw = addrF + (unsigned)(c * 4);
    const unsigned addrBw = addrB + (unsigned)(c * 4);

    f32x4 ra_[8], rb_[8];

    // ---- prologue: publish alpha_0, issue fwd reads (9 DS ops in flight) ----
    DS_WR(addrFw, stF);
    DS_RD8(ra_, addrF);

    for (int t0 = 1; t0 <= 241; t0 += 16) {   // 16 bodies x 16 steps = i = 1..256
        #pragma unroll
        for (int j = 0; j < 16; ++j) {

            // ---- SLOT O: publish bwd g_i | wait prev ra | issue bwd reads |
            //      shadow | fwd FMA step i ----
            DS_WR(addrBw, gB);
            LGKM1();                       // ra (prev slot) complete; aB write in flight
            DS_RD8(rb_, addrB);
            vnB[(j + 8) & 15] = wbq[(512 - ((t0 + j) + 8)) * 32 + c];  // in-bounds at tail
            float eoB_n = __builtin_exp2f(F2 * vnB[(j + 1) & 15]);
            {
                float a0 = aiF, a1 = 0.0f, a2 = 0.0f, a3 = 0.0f;
                aiF = 0.0f;
                #pragma unroll
                for (int k = 0; k < 8; ++k) {
                    f32x4 x = ra_[k];
                    a0 += x[0] * tcF[4 * k + 0]; a1 += x[1] * tcF[4 * k + 1];
                    a2 += x[2] * tcF[4 * k + 2]; a3 += x[3] * tcF[4 * k + 3];
                }
                float s = (a0 + a1) + (a2 + a3);
                stF = s * eoF_c;                  // fwd updates at all i = 1..256
            }
            if (j == 15) {
                // fwd rescale (every 16 steps) between update and publish;
                // its ds_swizzle fully drains lgkm (harmless, 1/16 steps)
                float m = grpmax32(stF);
                int e = ((__float_as_int(m) >> 23) & 0xff) - 127;
                stF *= __int_as_float((127 - e) << 23);
                scF += e;
            }

            // ---- SLOT E: publish fwd alpha_i | wait rb | issue fwd reads |
            //      shadow | bwd FMA step i ----
            DS_WR(addrFw, stF);
            LGKM1();                       // rb (slot O) complete; aF write in flight
            DS_RD8(ra_, addrF);
            vnF[(j + 8) & 15] = wbq[((t0 + j) + 8) * 32 + c];          // in-bounds at tail
            float eoF_n = __builtin_exp2f(F2 * vnF[(j + 1) & 15]);
            {
                float a0 = 0.0f, a1 = 0.0f, a2 = 0.0f, a3 = 0.0f;
                #pragma unroll
                for (int k = 0; k < 8; ++k) {
                    f32x4 x = rb_[k];
                    a0 += x[0] * tcB[4 * k + 0]; a1 += x[1] * tcB[4 * k + 1];
                    a2 += x[2] * tcB[4 * k + 2]; a3 += x[3] * tcB[4 * k + 3];
                }
                float s = (a0 + a1) + (a2 + a3);
                if (j == 15) stB = (t0 != 241) ? s : stB;  // i==256: fwd-only tail
                else         stB = s;
            }
            if (j == 15) {
                // bwd rescale at body end (before next publish)
                float m = grpmax32(stB);
                int e = ((__float_as_int(m) >> 23) & 0xff) - 127;
                stB *= __int_as_float((127 - e) << 23);
                scB += e;
            }
            gB    = stB * eoB_n;   // publish value for step i+1 (off write path)
            eoF_c = eoF_n;
        }
    }

    // drain our untracked asm DS ops before compiler-managed LDS traffic
    asm volatile("s_waitcnt lgkmcnt(0)");
    __builtin_amdgcn_sched_barrier(0);

    // ---- Z = sum_c af_256[c] * b_256[c], per 32-lane half ----
    float prod = stF * stB;
    prod += __shfl_xor(prod, 1);
    prod += __shfl_xor(prod, 2);
    prod += __shfl_xor(prod, 4);
    prod += __shfl_xor(prod, 8);
    prod += __shfl_xor(prod, 16);
    float total = ((float)(scF + scB + BIASCNT) + __builtin_log2f(prod)) * LN2;

    // ---- gold-path score epilogue: all 64 lanes per batch, gathers L2/L3-warm ----
    float ps0 = 0.0f, ps1 = 0.0f;
    #pragma unroll
    for (int bb = 0; bb < 2; ++bb) {
        const float* w  = wtv + (size_t)(bbase + bb) * (512 * 32);
        const int*   tg = ltag + (bb << 9);
        int   tcur[8];
        float em[8];
        #pragma unroll
        for (int k = 0; k < 8; ++k) tcur[k] = tg[l + 64 * k];
        #pragma unroll
        for (int k = 0; k < 8; ++k) em[k] = w[(l + 64 * k) * 32 + (tcur[k] - 1)];
        float acc = 0.0f;
        #pragma unroll
        for (int k = 0; k < 8; ++k) {
            int t  = l + 64 * k;
            int nx = tg[(t + 1) & 511];
            nx = (t == 511) ? 33 : nx;            // end term trans[tag_511][STOP]
            acc += em[k] + tlds[tcur[k] * 34 + nx];
        }
        if (l == 0) acc += tlds[tg[0]];           // start term trans[0][tag_0]
        acc += __shfl_xor(acc, 1);
        acc += __shfl_xor(acc, 2);
        acc += __shfl_xor(acc, 4);
        acc += __shfl_xor(acc, 8);
        acc += __shfl_xor(acc, 16);
        acc += __shfl_xor(acc, 32);
        if (bb == 0) ps0 = acc; else ps1 = acc;
    }
    float ps = (q == 0) ? ps0 : ps1;
    if (c == 0) out[bbase + q] = total - ps;      // lanes 0 and 32 write
}

extern "C" void kernel_launch(void* const* d_in, const int* in_sizes, int n_in,
                              void* d_out, int out_size, void* d_ws, size_t ws_size,
                              hipStream_t stream) {
    const float* wtv   = (const float*)d_in[0];
    const float* trans = (const float*)d_in[1];
    const int*   rtag  = (const int*)d_in[2];
    (void)in_sizes; (void)n_in; (void)d_ws; (void)ws_size; (void)out_size;
    float* out = (float*)d_out;
    crf_kernel<<<256, 64, 0, stream>>>(wtv, trans, rtag, out);
}